// Round 1
// baseline (482.243 us; speedup 1.0000x reference)
//
#include <hip/hip_runtime.h>
#include <hip/hip_bf16.h>

typedef __hip_bfloat16 bf16;
typedef short short8 __attribute__((ext_vector_type(8)));   // 4 VGPRs = 8 bf16
typedef float f32x4 __attribute__((ext_vector_type(4)));

constexpr int Bn = 8, Sn = 2048, Dn = 1024;
constexpr int BM = 128, BN = 128, BK = 32;

// ---------------- cast fp32 -> bf16, vectorized ----------------
__global__ void cast_f32_bf16_k(const float* __restrict__ x, bf16* __restrict__ y, int n) {
  int i = (blockIdx.x * blockDim.x + threadIdx.x) * 4;
  if (i >= n) return;
  float4 f = *reinterpret_cast<const float4*>(x + i);
  bf16 tmp[4] = {__float2bfloat16(f.x), __float2bfloat16(f.y),
                 __float2bfloat16(f.z), __float2bfloat16(f.w)};
  *reinterpret_cast<short4*>(y + i) = *reinterpret_cast<const short4*>(tmp);
}

// ---------------- transpose+cast V: [B][S][D] f32 -> [B][D][S] bf16 ----------------
__global__ void transpose_cast_v_k(const float* __restrict__ v, bf16* __restrict__ vt) {
  __shared__ float tile[32][33];
  const int s0 = blockIdx.x * 32, d0 = blockIdx.y * 32, b = blockIdx.z;
  const float* src = v + (size_t)b * Sn * Dn;
  bf16* dst = vt + (size_t)b * Dn * Sn;
  const int tx = threadIdx.x & 31, ty = threadIdx.x >> 5;
  #pragma unroll
  for (int i = 0; i < 4; ++i) {
    int s = ty + i * 8;
    tile[s][tx] = src[(size_t)(s0 + s) * Dn + d0 + tx];
  }
  __syncthreads();
  #pragma unroll
  for (int i = 0; i < 4; ++i) {
    int d = ty + i * 8;
    dst[(size_t)(d0 + d) * Sn + s0 + tx] = __float2bfloat16(tile[tx][d]);
  }
}

// ---------------- GEMM: C[M,N] = A[M,K] @ BT[N,K]^T  (both row-major, B-transposed layout)
// EPI 0: C_bf16 = acc + bias[col]
// EPI 1: C_bf16 = acc*scale + mask[row*N+col]
// EPI 2: C_f32  = acc
template<int EPI>
__global__ __launch_bounds__(256, 2)
void gemm_bt_k(const bf16* __restrict__ A, const bf16* __restrict__ BT,
               void* __restrict__ Cv, const float* __restrict__ aux,
               int M, int N, int K,
               long long sAz, long long sBz, long long sCz, float scale)
{
  __shared__ bf16 lA[BM * BK];
  __shared__ bf16 lB[BN * BK];
  const int t = threadIdx.x;
  const int w = t >> 6;
  const int lane = t & 63;
  const int z = blockIdx.z;
  const bf16* Ab = A + (size_t)z * sAz;
  const bf16* Bb = BT + (size_t)z * sBz;
  const int m0 = blockIdx.y * BM;
  const int n0 = blockIdx.x * BN;
  const int wm = (w >> 1) * 64, wn = (w & 1) * 64;   // 2x2 wave grid, 64x64 per wave
  const int fr = lane & 15;                           // fragment row (A row / BT row)
  const int k8 = (lane >> 4) * 8;                     // k-offset within BK=32

  f32x4 acc[4][4];
  const f32x4 fzero = {0.f, 0.f, 0.f, 0.f};
  #pragma unroll
  for (int i = 0; i < 4; ++i)
    #pragma unroll
    for (int j = 0; j < 4; ++j) acc[i][j] = fzero;

  const int nkt = K / BK;
  for (int kt = 0; kt < nkt; ++kt) {
    const int kb = kt * BK;
    // stage A/B tiles: 128 rows x 32 cols bf16 = 8KB each; 512 16B-slots; 256 thr -> 2 issues
    #pragma unroll
    for (int i = 0; i < 2; ++i) {
      const int idx = i * 256 + t;
      const int row = idx >> 2, cc = idx & 3;
      const bf16* ga = Ab + (size_t)(m0 + row) * K + kb + cc * 8;
      __builtin_amdgcn_global_load_lds(
          (__attribute__((address_space(1))) void*)ga,
          (__attribute__((address_space(3))) void*)&lA[(i * 256 + w * 64) * 8],
          16, 0, 0);
      const bf16* gb = Bb + (size_t)(n0 + row) * K + kb + cc * 8;
      __builtin_amdgcn_global_load_lds(
          (__attribute__((address_space(1))) void*)gb,
          (__attribute__((address_space(3))) void*)&lB[(i * 256 + w * 64) * 8],
          16, 0, 0);
    }
    asm volatile("s_waitcnt vmcnt(0)" ::: "memory");
    __syncthreads();

    short8 af[4], bfv[4];
    #pragma unroll
    for (int mi = 0; mi < 4; ++mi)
      af[mi] = *reinterpret_cast<const short8*>(&lA[(wm + mi * 16 + fr) * BK + k8]);
    #pragma unroll
    for (int ni = 0; ni < 4; ++ni)
      bfv[ni] = *reinterpret_cast<const short8*>(&lB[(wn + ni * 16 + fr) * BK + k8]);
    #pragma unroll
    for (int mi = 0; mi < 4; ++mi)
      #pragma unroll
      for (int ni = 0; ni < 4; ++ni)
        asm("v_mfma_f32_16x16x32_bf16 %0, %1, %2, %0"
            : "+v"(acc[mi][ni]) : "v"(af[mi]), "v"(bfv[ni]));
    __syncthreads();
  }

  // epilogue: lane holds D[(lane>>4)*4 + r][lane&15] per 16x16 fragment
  const int or0 = (lane >> 4) * 4;
  const int oc = fr;
  if constexpr (EPI == 0) {
    bf16* C = (bf16*)Cv + (size_t)z * sCz;
    #pragma unroll
    for (int mi = 0; mi < 4; ++mi)
      #pragma unroll
      for (int r = 0; r < 4; ++r) {
        const int row = m0 + wm + mi * 16 + or0 + r;
        #pragma unroll
        for (int ni = 0; ni < 4; ++ni) {
          const int col = n0 + wn + ni * 16 + oc;
          C[(size_t)row * N + col] = __float2bfloat16(acc[mi][ni][r] + aux[col]);
        }
      }
  } else if constexpr (EPI == 1) {
    bf16* C = (bf16*)Cv + (size_t)z * sCz;
    #pragma unroll
    for (int mi = 0; mi < 4; ++mi)
      #pragma unroll
      for (int r = 0; r < 4; ++r) {
        const int row = m0 + wm + mi * 16 + or0 + r;
        #pragma unroll
        for (int ni = 0; ni < 4; ++ni) {
          const int col = n0 + wn + ni * 16 + oc;
          float v = acc[mi][ni][r] * scale + aux[(size_t)row * N + col];
          C[(size_t)row * N + col] = __float2bfloat16(v);
        }
      }
  } else {
    float* C = (float*)Cv + (size_t)z * sCz;
    #pragma unroll
    for (int mi = 0; mi < 4; ++mi)
      #pragma unroll
      for (int r = 0; r < 4; ++r) {
        const int row = m0 + wm + mi * 16 + or0 + r;
        #pragma unroll
        for (int ni = 0; ni < 4; ++ni) {
          const int col = n0 + wn + ni * 16 + oc;
          C[(size_t)row * N + col] = acc[mi][ni][r];
        }
      }
  }
}

// ---------------- row softmax over 2048 bf16, in place ----------------
__global__ __launch_bounds__(256)
void softmax_rows_k(bf16* __restrict__ sc) {
  const size_t row = blockIdx.x;
  bf16* p = sc + row * (size_t)Sn;
  const int t = threadIdx.x;
  unsigned short raw[8];
  *reinterpret_cast<int4*>(raw) = *reinterpret_cast<const int4*>(p + t * 8);
  float x[8];
  float m = -1e30f;
  #pragma unroll
  for (int j = 0; j < 8; ++j) {
    x[j] = __uint_as_float(((unsigned)raw[j]) << 16);
    m = fmaxf(m, x[j]);
  }
  #pragma unroll
  for (int off = 32; off >= 1; off >>= 1) m = fmaxf(m, __shfl_xor(m, off));
  __shared__ float sred[4], ssum[4];
  const int w = t >> 6;
  if ((t & 63) == 0) sred[w] = m;
  __syncthreads();
  m = fmaxf(fmaxf(sred[0], sred[1]), fmaxf(sred[2], sred[3]));
  float e[8], s = 0.f;
  #pragma unroll
  for (int j = 0; j < 8; ++j) { e[j] = __expf(x[j] - m); s += e[j]; }
  #pragma unroll
  for (int off = 32; off >= 1; off >>= 1) s += __shfl_xor(s, off);
  if ((t & 63) == 0) ssum[w] = s;
  __syncthreads();
  s = (ssum[0] + ssum[1]) + (ssum[2] + ssum[3]);
  const float inv = 1.f / s;
  unsigned short o[8];
  #pragma unroll
  for (int j = 0; j < 8; ++j) {
    bf16 hv = __float2bfloat16(e[j] * inv);
    o[j] = *reinterpret_cast<unsigned short*>(&hv);
  }
  *reinterpret_cast<int4*>(p + t * 8) = *reinterpret_cast<const int4*>(o);
}

extern "C" void kernel_launch(void* const* d_in, const int* in_sizes, int n_in,
                              void* d_out, int out_size, void* d_ws, size_t ws_size,
                              hipStream_t stream) {
  const float* q    = (const float*)d_in[0];
  const float* k    = (const float*)d_in[1];
  const float* v1   = (const float*)d_in[2];
  const float* mask = (const float*)d_in[3];
  const float* W1   = (const float*)d_in[4];
  const float* b1   = (const float*)d_in[5];
  const float* W2   = (const float*)d_in[6];
  const float* b2   = (const float*)d_in[7];
  float* out = (float*)d_out;

  const size_t nQKD = (size_t)Bn * Sn * Dn;   // 16,777,216
  char* ws = (char*)d_ws;
  // layout: [qk bf16 (q then k, contiguous)] [vt] [h] [w1] [w2] [scores]
  bf16* qkb = (bf16*)ws;                      // 2*nQKD elements (q rows then k rows)
  bf16* qb  = qkb;
  bf16* kb  = qkb + nQKD;
  bf16* vtb = qkb + 2 * nQKD;                 // [B][D][S]
  bf16* hb  = vtb + nQKD;                     // 2*nQKD elements (h for q and k)
  bf16* w1b = hb + 2 * nQKD;
  bf16* w2b = w1b + (size_t)Dn * Dn;
  bf16* scb = w2b + (size_t)Dn * Dn;          // [B][S][S]

  dim3 blk(256);
  const int nQK = (int)nQKD;
  cast_f32_bf16_k<<<dim3(nQK / 4 / 256), blk, 0, stream>>>(q, qb, nQK);
  cast_f32_bf16_k<<<dim3(nQK / 4 / 256), blk, 0, stream>>>(k, kb, nQK);
  cast_f32_bf16_k<<<dim3(Dn * Dn / 4 / 256), blk, 0, stream>>>(W1, w1b, Dn * Dn);
  cast_f32_bf16_k<<<dim3(Dn * Dn / 4 / 256), blk, 0, stream>>>(W2, w2b, Dn * Dn);
  transpose_cast_v_k<<<dim3(Sn / 32, Dn / 32, Bn), blk, 0, stream>>>(v1, vtb);

  const int M2 = 2 * Bn * Sn;  // 32768: q-rows and k-rows projected together
  // h = [q;k] @ W1^T + b1
  gemm_bt_k<0><<<dim3(Dn / BN, M2 / BM, 1), blk, 0, stream>>>(
      qkb, w1b, hb, b1, M2, Dn, Dn, 0, 0, 0, 1.f);
  // [qp;kp] = h @ W2^T + b2  (overwrites qkb)
  gemm_bt_k<0><<<dim3(Dn / BN, M2 / BM, 1), blk, 0, stream>>>(
      hb, w2b, qkb, b2, M2, Dn, Dn, 0, 0, 0, 1.f);
  // scores = qp @ kp^T * (1/32) + mask   [B][S][S] bf16
  gemm_bt_k<1><<<dim3(Sn / BN, Sn / BM, Bn), blk, 0, stream>>>(
      qb, kb, scb, mask, Sn, Sn, Dn,
      (long long)Sn * Dn, (long long)Sn * Dn, (long long)Sn * Sn, 0.03125f);
  // softmax rows, in place
  softmax_rows_k<<<dim3(Bn * Sn), blk, 0, stream>>>(scb);
  // out = P @ V  via VT (B^T layout), fp32 epilogue
  gemm_bt_k<2><<<dim3(Dn / BN, Sn / BM, Bn), blk, 0, stream>>>(
      scb, vtb, out, nullptr, Sn, Dn, Sn,
      (long long)Sn * Sn, (long long)Dn * Sn, (long long)Sn * Dn, 1.f);
}

// Round 2
// 387.487 us; speedup vs baseline: 1.2445x; 1.2445x over previous
//
#include <hip/hip_runtime.h>
#include <hip/hip_bf16.h>

typedef __hip_bfloat16 bf16;
typedef short short8 __attribute__((ext_vector_type(8)));   // 4 VGPRs = 8 bf16
typedef float f32x4 __attribute__((ext_vector_type(4)));

constexpr int Bn = 8, Sn = 2048, Dn = 1024;
constexpr int BM = 256, BN = 256, BK = 64;

// ---------------- cast fp32 -> bf16, vectorized ----------------
__global__ void cast_f32_bf16_k(const float* __restrict__ x, bf16* __restrict__ y, int n) {
  int i = (blockIdx.x * blockDim.x + threadIdx.x) * 4;
  if (i >= n) return;
  float4 f = *reinterpret_cast<const float4*>(x + i);
  bf16 tmp[4] = {__float2bfloat16(f.x), __float2bfloat16(f.y),
                 __float2bfloat16(f.z), __float2bfloat16(f.w)};
  *reinterpret_cast<short4*>(y + i) = *reinterpret_cast<const short4*>(tmp);
}

// ---------------- transpose+cast V: [B][S][D] f32 -> [B][D][S] bf16 ----------------
__global__ void transpose_cast_v_k(const float* __restrict__ v, bf16* __restrict__ vt) {
  __shared__ float tile[32][33];
  const int s0 = blockIdx.x * 32, d0 = blockIdx.y * 32, b = blockIdx.z;
  const float* src = v + (size_t)b * Sn * Dn;
  bf16* dst = vt + (size_t)b * Dn * Sn;
  const int tx = threadIdx.x & 31, ty = threadIdx.x >> 5;
  #pragma unroll
  for (int i = 0; i < 4; ++i) {
    int s = ty + i * 8;
    tile[s][tx] = src[(size_t)(s0 + s) * Dn + d0 + tx];
  }
  __syncthreads();
  #pragma unroll
  for (int i = 0; i < 4; ++i) {
    int d = ty + i * 8;
    dst[(size_t)(d0 + d) * Sn + s0 + tx] = __float2bfloat16(tile[tx][d]);
  }
}

// ---------------- 256x256x64 8-phase GEMM: C[M,N] = A[M,K] @ BT[N,K]^T ----------------
// EPI 0: C_bf16 = acc + bias[col]
// EPI 1: C_bf16 = acc*scale + mask[row*N+col]
// EPI 2: C_f32  = acc
// LDS element-offset map: A(buf) = buf*16384 ; B(buf) = 32768 + buf*16384
#define BARRIER() asm volatile("s_barrier" ::: "memory")

#define QUAD(ms, ns) do {                                                     \
    __builtin_amdgcn_s_setprio(1);                                            \
    _Pragma("unroll")                                                         \
    for (int mi4 = 0; mi4 < 4; ++mi4) {                                       \
      _Pragma("unroll")                                                       \
      for (int n2 = 0; n2 < 2; ++n2) {                                        \
        _Pragma("unroll")                                                     \
        for (int kk = 0; kk < 2; ++kk)                                        \
          asm volatile("v_mfma_f32_16x16x32_bf16 %0, %1, %2, %0"              \
                       : "+v"(acc[(ms)*4+mi4][(ns)*2+n2])                     \
                       : "v"(aF[mi4][kk]), "v"(bF[(ns)*2+n2][kk]));           \
      }                                                                       \
    }                                                                         \
    __builtin_amdgcn_s_setprio(0);                                            \
  } while (0)

#define RD_A(buf, ms) do {                                                    \
    _Pragma("unroll")                                                         \
    for (int mi4 = 0; mi4 < 4; ++mi4) {                                       \
      aF[mi4][0] = rdA(buf, ms, mi4, 0);                                      \
      aF[mi4][1] = rdA(buf, ms, mi4, 1);                                      \
    }                                                                         \
  } while (0)

#define RD_B(buf, ns) do {                                                    \
    bF[(ns)*2  ][0] = rdB(buf, ns, 0, 0);                                     \
    bF[(ns)*2  ][1] = rdB(buf, ns, 0, 1);                                     \
    bF[(ns)*2+1][0] = rdB(buf, ns, 1, 0);                                     \
    bF[(ns)*2+1][1] = rdB(buf, ns, 1, 1);                                     \
  } while (0)

template<int EPI>
__global__ __launch_bounds__(512, 2)
void gemm256_k(const bf16* __restrict__ A, const bf16* __restrict__ BT,
               void* __restrict__ Cv, const float* __restrict__ aux,
               int N, int K, long long sAz, long long sBz, long long sCz,
               float scale, int gx, int gy)
{
  __shared__ __align__(128) bf16 sh[4 * 16384];   // 128 KiB: A0 A1 B0 B1

  // T1: XCD-aware bijective swizzle of the flat block id (nwg % 8 == 0 for all launches)
  const int nwg = (int)gridDim.x;
  const int flat = (int)blockIdx.x;
  const int swz = (flat & 7) * (nwg >> 3) + (flat >> 3);
  const int tn = swz % gx;
  const int rem = swz / gx;
  const int tm = rem % gy;
  const int z  = rem / gy;

  const int t = threadIdx.x, w = t >> 6, lane = t & 63;
  const int wm = w >> 2, wn = w & 3;              // 2 x 4 wave grid; wave tile 128x64
  const int fr = lane & 15, kg = lane >> 4;
  const int m0 = tm * BM, n0 = tn * BN;
  const bf16* Abase = A + (size_t)z * sAz + (size_t)m0 * K;
  const bf16* Bbase = BT + (size_t)z * sBz + (size_t)n0 * K;

  f32x4 acc[8][4];
  const f32x4 fz = {0.f, 0.f, 0.f, 0.f};
  #pragma unroll
  for (int i = 0; i < 8; ++i)
    #pragma unroll
    for (int j = 0; j < 4; ++j) acc[i][j] = fz;
  short8 aF[4][2], bF[4][2];

  // stage one half-tile (128 rows x 64 cols) into LDS, linear dest + source-swizzled cols
  auto stage = [&](int dstElemBase, const bf16* gbase, int half, int kt) {
    const bf16* g0 = gbase + (size_t)(half * 128) * K + (size_t)kt * BK;
    bf16* db = (bf16*)sh + dstElemBase + half * 8192;
    #pragma unroll
    for (int i = 0; i < 2; ++i) {
      const int s0 = i * 512 + w * 64;
      const int slot = s0 + lane;
      const int row = slot >> 3;
      const int cb = (slot & 7) ^ (row & 7);       // inverse of read-side XOR swizzle
      const bf16* src = g0 + (size_t)row * K + cb * 8;
      __builtin_amdgcn_global_load_lds((__attribute__((address_space(1))) void*)src,
          (__attribute__((address_space(3))) void*)(db + s0 * 8), 16, 0, 0);
    }
  };
  // swizzled fragment reads (ds_read_b128); tile-local byte ^= (row&7)<<4
  auto rdA = [&](int buf, int ms, int mi4, int kk) -> short8 {
    const int row = wm * 128 + ms * 64 + mi4 * 16 + fr;
    int loc = row * 128 + kk * 64 + kg * 16;
    loc ^= (row & 7) << 4;
    return *reinterpret_cast<const short8*>((const char*)sh + buf * 32768 + loc);
  };
  auto rdB = [&](int buf, int ns, int j, int kk) -> short8 {
    const int row = wn * 64 + ns * 32 + j * 16 + fr;
    int loc = row * 128 + kk * 64 + kg * 16;
    loc ^= (row & 7) << 4;
    return *reinterpret_cast<const short8*>((const char*)sh + 65536 + buf * 32768 + loc);
  };

  const int NT = K / BK;
  // prologue: tile0 (B,A) -> buf0 ; tile1 B -> buf1 ; wait tile0 landed (4 left in flight)
  stage(32768, Bbase, 0, 0); stage(32768, Bbase, 1, 0);
  stage(0,     Abase, 0, 0); stage(0,     Abase, 1, 0);
  stage(49152, Bbase, 0, 1); stage(49152, Bbase, 1, 1);
  asm volatile("s_waitcnt vmcnt(4)" ::: "memory");
  BARRIER();

  int T = 0;
  for (; T < NT - 2; T += 2) {
    // ---- tile T in buf0 ----
    RD_A(0, 0); RD_B(0, 0);
    stage(16384, Abase, 0, T + 1);                 // A-lo(T+1) -> buf1
    BARRIER(); QUAD(0, 0); BARRIER();

    RD_B(0, 1);
    stage(16384, Abase, 1, T + 1);                 // A-hi(T+1) -> buf1
    BARRIER(); QUAD(0, 1); BARRIER();

    RD_A(0, 1);
    stage(32768, Bbase, 0, T + 2);                 // B-lo(T+2) -> buf0 (B reads done ph2)
    BARRIER(); QUAD(1, 0); BARRIER();

    stage(32768, Bbase, 1, T + 2);                 // B-hi(T+2) -> buf0
    asm volatile("s_waitcnt vmcnt(4)" ::: "memory"); // tile T+1 fully landed
    BARRIER(); QUAD(1, 1); BARRIER();

    // ---- tile T+1 in buf1 ----
    RD_A(1, 0); RD_B(1, 0);
    stage(0, Abase, 0, T + 2);                     // A-lo(T+2) -> buf0 (A reads done ph3)
    BARRIER(); QUAD(0, 0); BARRIER();

    RD_B(1, 1);
    stage(0, Abase, 1, T + 2);                     // A-hi(T+2) -> buf0
    BARRIER(); QUAD(0, 1); BARRIER();

    RD_A(1, 1);
    stage(49152, Bbase, 0, T + 3);                 // B-lo(T+3) -> buf1
    BARRIER(); QUAD(1, 0); BARRIER();

    stage(49152, Bbase, 1, T + 3);                 // B-hi(T+3) -> buf1
    asm volatile("s_waitcnt vmcnt(4)" ::: "memory"); // tile T+2 fully landed
    BARRIER(); QUAD(1, 1); BARRIER();
  }
  // ---- peeled last pair: tiles T (buf0), T+1 (buf1); no further prefetch ----
  {
    RD_A(0, 0); RD_B(0, 0);
    stage(16384, Abase, 0, T + 1);
    BARRIER(); QUAD(0, 0); BARRIER();

    RD_B(0, 1);
    stage(16384, Abase, 1, T + 1);
    BARRIER(); QUAD(0, 1); BARRIER();

    RD_A(0, 1);
    BARRIER(); QUAD(1, 0); BARRIER();

    asm volatile("s_waitcnt vmcnt(0)" ::: "memory"); // tile T+1 fully landed
    BARRIER(); QUAD(1, 1); BARRIER();

    RD_A(1, 0); RD_B(1, 0);
    BARRIER(); QUAD(0, 0); BARRIER();

    RD_B(1, 1);
    BARRIER(); QUAD(0, 1); BARRIER();

    RD_A(1, 1);
    BARRIER(); QUAD(1, 0); BARRIER();

    BARRIER(); QUAD(1, 1); BARRIER();
  }

  // epilogue: frag (mi,ni): C[m0+wm*128+mi*16+kg*4+r][n0+wn*64+ni*16+fr]
  const int or0 = kg * 4;
  if constexpr (EPI == 0) {
    bf16* C = (bf16*)Cv + (size_t)z * sCz;
    #pragma unroll
    for (int mi = 0; mi < 8; ++mi)
      #pragma unroll
      for (int r = 0; r < 4; ++r) {
        const int row = m0 + wm * 128 + mi * 16 + or0 + r;
        #pragma unroll
        for (int ni = 0; ni < 4; ++ni) {
          const int col = n0 + wn * 64 + ni * 16 + fr;
          C[(size_t)row * N + col] = __float2bfloat16(acc[mi][ni][r] + aux[col]);
        }
      }
  } else if constexpr (EPI == 1) {
    bf16* C = (bf16*)Cv + (size_t)z * sCz;
    #pragma unroll
    for (int mi = 0; mi < 8; ++mi)
      #pragma unroll
      for (int r = 0; r < 4; ++r) {
        const int row = m0 + wm * 128 + mi * 16 + or0 + r;
        #pragma unroll
        for (int ni = 0; ni < 4; ++ni) {
          const int col = n0 + wn * 64 + ni * 16 + fr;
          float v = acc[mi][ni][r] * scale + aux[(size_t)row * N + col];
          C[(size_t)row * N + col] = __float2bfloat16(v);
        }
      }
  } else {
    float* C = (float*)Cv + (size_t)z * sCz;
    #pragma unroll
    for (int mi = 0; mi < 8; ++mi)
      #pragma unroll
      for (int r = 0; r < 4; ++r) {
        const int row = m0 + wm * 128 + mi * 16 + or0 + r;
        #pragma unroll
        for (int ni = 0; ni < 4; ++ni) {
          const int col = n0 + wn * 64 + ni * 16 + fr;
          C[(size_t)row * N + col] = acc[mi][ni][r];
        }
      }
  }
}

// ---------------- row softmax over 2048 bf16, in place ----------------
__global__ __launch_bounds__(256)
void softmax_rows_k(bf16* __restrict__ sc) {
  const size_t row = blockIdx.x;
  bf16* p = sc + row * (size_t)Sn;
  const int t = threadIdx.x;
  unsigned short raw[8];
  *reinterpret_cast<int4*>(raw) = *reinterpret_cast<const int4*>(p + t * 8);
  float x[8];
  float m = -1e30f;
  #pragma unroll
  for (int j = 0; j < 8; ++j) {
    x[j] = __uint_as_float(((unsigned)raw[j]) << 16);
    m = fmaxf(m, x[j]);
  }
  #pragma unroll
  for (int off = 32; off >= 1; off >>= 1) m = fmaxf(m, __shfl_xor(m, off));
  __shared__ float sred[4], ssum[4];
  const int w = t >> 6;
  if ((t & 63) == 0) sred[w] = m;
  __syncthreads();
  m = fmaxf(fmaxf(sred[0], sred[1]), fmaxf(sred[2], sred[3]));
  float e[8], s = 0.f;
  #pragma unroll
  for (int j = 0; j < 8; ++j) { e[j] = __expf(x[j] - m); s += e[j]; }
  #pragma unroll
  for (int off = 32; off >= 1; off >>= 1) s += __shfl_xor(s, off);
  if ((t & 63) == 0) ssum[w] = s;
  __syncthreads();
  s = (ssum[0] + ssum[1]) + (ssum[2] + ssum[3]);
  const float inv = 1.f / s;
  unsigned short o[8];
  #pragma unroll
  for (int j = 0; j < 8; ++j) {
    bf16 hv = __float2bfloat16(e[j] * inv);
    o[j] = *reinterpret_cast<unsigned short*>(&hv);
  }
  *reinterpret_cast<int4*>(p + t * 8) = *reinterpret_cast<const int4*>(o);
}

extern "C" void kernel_launch(void* const* d_in, const int* in_sizes, int n_in,
                              void* d_out, int out_size, void* d_ws, size_t ws_size,
                              hipStream_t stream) {
  const float* q    = (const float*)d_in[0];
  const float* k    = (const float*)d_in[1];
  const float* v1   = (const float*)d_in[2];
  const float* mask = (const float*)d_in[3];
  const float* W1   = (const float*)d_in[4];
  const float* b1   = (const float*)d_in[5];
  const float* W2   = (const float*)d_in[6];
  const float* b2   = (const float*)d_in[7];
  float* out = (float*)d_out;

  const size_t nQKD = (size_t)Bn * Sn * Dn;   // 16,777,216
  char* ws = (char*)d_ws;
  bf16* qkb = (bf16*)ws;                      // [q;k] bf16, 2*nQKD
  bf16* qb  = qkb;
  bf16* kb  = qkb + nQKD;
  bf16* vtb = qkb + 2 * nQKD;                 // [B][D][S]
  bf16* hb  = vtb + nQKD;                     // hidden for [q;k]
  bf16* w1b = hb + 2 * nQKD;
  bf16* w2b = w1b + (size_t)Dn * Dn;
  bf16* scb = w2b + (size_t)Dn * Dn;          // [B][S][S]

  dim3 blk(256);
  const int nQK = (int)nQKD;
  cast_f32_bf16_k<<<dim3(nQK / 4 / 256), blk, 0, stream>>>(q, qb, nQK);
  cast_f32_bf16_k<<<dim3(nQK / 4 / 256), blk, 0, stream>>>(k, kb, nQK);
  cast_f32_bf16_k<<<dim3(Dn * Dn / 4 / 256), blk, 0, stream>>>(W1, w1b, Dn * Dn);
  cast_f32_bf16_k<<<dim3(Dn * Dn / 4 / 256), blk, 0, stream>>>(W2, w2b, Dn * Dn);
  transpose_cast_v_k<<<dim3(Sn / 32, Dn / 32, Bn), blk, 0, stream>>>(v1, vtb);

  const int M2 = 2 * Bn * Sn;  // 32768 rows ([q;k] together)
  dim3 gblk(512);
  // h = [q;k] @ W1^T + b1 : grid 4 x 128 = 512
  gemm256_k<0><<<dim3(4 * (M2 / BM)), gblk, 0, stream>>>(
      qkb, w1b, hb, b1, Dn, Dn, 0, 0, 0, 1.f, 4, M2 / BM);
  // [qp;kp] = h @ W2^T + b2
  gemm256_k<0><<<dim3(4 * (M2 / BM)), gblk, 0, stream>>>(
      hb, w2b, qkb, b2, Dn, Dn, 0, 0, 0, 1.f, 4, M2 / BM);
  // scores = qp @ kp^T * (1/32) + mask : grid 8 x 8 x 8 = 512
  gemm256_k<1><<<dim3(8 * 8 * Bn), gblk, 0, stream>>>(
      qb, kb, scb, mask, Sn, Dn,
      (long long)Sn * Dn, (long long)Sn * Dn, (long long)Sn * Sn, 0.03125f, 8, 8);
  // softmax rows, in place
  softmax_rows_k<<<dim3(Bn * Sn), blk, 0, stream>>>(scb);
  // out = P @ V via VT : grid 4 x 8 x 8 = 256
  gemm256_k<2><<<dim3(4 * 8 * Bn), gblk, 0, stream>>>(
      scb, vtb, out, nullptr, Dn, Sn,
      (long long)Sn * Sn, (long long)Dn * Sn, (long long)Sn * Dn, 1.f, 4, 8);
}